// Round 4
// baseline (7213.409 us; speedup 1.0000x reference)
//
#include <hip/hip_runtime.h>
#include <cstdint>
#include <cstddef>

#define A_N 100000
#define B_N 200000
#define M_N 20000
#define HD 256
#define MAX_NB 10
#define N_MOLS 2000
#define ATOM_FDIM 35
#define FB_DIM 40

#define BM 64
#define BN 128
#define BK 32

// Static device buffers — no assumptions about ws_size.
__device__ float g_msg0[(size_t)B_N * HD];
__device__ float g_msg1[(size_t)B_N * HD];
__device__ float g_counts[N_MOLS];

// ---------------- zero fill ----------------
__global__ __launch_bounds__(256)
void k_zero_out(float* __restrict__ p, int n)
{
    const int i = blockIdx.x * 256 + threadIdx.x;
    if (i < n) p[i] = 0.f;
}

__global__ __launch_bounds__(256)
void k_zero_counts()
{
    const int i = blockIdx.x * 256 + threadIdx.x;
    if (i < N_MOLS) g_counts[i] = 0.f;
}

// ---------------- K1: g_msg0 = relu(fbonds @ W_i) ----------------
__global__ __launch_bounds__(256)
void k_in(const float* __restrict__ fbonds, const float* __restrict__ Wi)
{
    __shared__ float Ws[FB_DIM * HD];                      // 40 KB
    for (int i = threadIdx.x; i < FB_DIM * HD; i += 256) Ws[i] = Wi[i];
    __syncthreads();
    const int lane = threadIdx.x & 63;
    const int wid  = (blockIdx.x * 256 + threadIdx.x) >> 6;
    const int nw   = (gridDim.x * 256) >> 6;
    for (int row = wid; row < B_N; row += nw) {
        const float* fr = fbonds + (size_t)row * FB_DIM;
        float ax = 0.f, ay = 0.f, az = 0.f, aw = 0.f;
        #pragma unroll
        for (int q = 0; q < FB_DIM / 4; ++q) {
            const float4 fv = *(const float4*)(fr + q * 4);
            const float fa[4] = {fv.x, fv.y, fv.z, fv.w};
            #pragma unroll
            for (int t = 0; t < 4; ++t) {
                const float4 w = *(const float4*)&Ws[(q * 4 + t) * HD + lane * 4];
                ax += fa[t] * w.x; ay += fa[t] * w.y;
                az += fa[t] * w.z; aw += fa[t] * w.w;
            }
        }
        float4 r; r.x = fmaxf(ax, 0.f); r.y = fmaxf(ay, 0.f);
        r.z = fmaxf(az, 0.f); r.w = fmaxf(aw, 0.f);
        *(float4*)(g_msg0 + (size_t)row * HD + lane * 4) = r;
    }
}

// ------- K2 (x2): dst = relu(fbonds@W_i + gather(bgraph,[tmsg;src]) @ W_h) -------
// Neighbor pointers resolved ONCE into LDS (ptr_s) — round-3 held them in
// registers, blowing VGPR to 256 and spilling 2.2 GB/dispatch to scratch.
__global__ __launch_bounds__(256)
void k_mp(const int* __restrict__ bgraph, const float* __restrict__ tmsg,
          const float* __restrict__ Wh, const float* __restrict__ fbonds,
          const float* __restrict__ Wi, int srcSel)
{
    const float* gsrc = srcSel ? g_msg1 : g_msg0;
    float* gdst       = srcSel ? g_msg0 : g_msg1;

    __shared__ float As[BK][BM + 4];            // 8.5 KB
    __shared__ float Bs[BK][BN + 4];            // 16.5 KB
    __shared__ float wi_s[FB_DIM][BN];          // 20 KB
    __shared__ const float* ptr_s[BM][MAX_NB];  // 5 KB
    const int tid = threadIdx.x;
    const int rowBase = blockIdx.x * BM;
    const int colBase = blockIdx.y * BN;

    // resolve neighbor pointers into LDS (640 entries)
    for (int idx = tid; idx < BM * MAX_NB; idx += 256) {
        const int r = idx / MAX_NB;
        const int j = idx - r * MAX_NB;
        const int id = bgraph[(size_t)(rowBase + r) * MAX_NB + j];
        ptr_s[r][j] = (id < M_N) ? (tmsg + (size_t)id * HD)
                                 : (gsrc + (size_t)(id - M_N) * HD);
    }
    // stage W_i tile for epilogue: 40x128 floats = 1280 float4, 5 per thread
    #pragma unroll
    for (int i = 0; i < 5; ++i) {
        const int idx = tid + i * 256;
        const int k = idx >> 5;
        const int c = (idx & 31) << 2;
        *(float4*)&wi_s[k][c] = *(const float4*)(Wi + (size_t)k * HD + colBase + c);
    }
    __syncthreads();

    const int r0 = tid >> 3;               // [0,32)
    const int kq = (tid & 7) << 2;         // {0,4,...,28}
    const int tx = tid & 15;
    const int ty = tid >> 4;
    float acc[4][8] = {};

    for (int k0 = 0; k0 < HD; k0 += BK) {
        // A-tile: gather-sum of 10 neighbor rows (pointers from LDS)
        float4 s0 = {0.f, 0.f, 0.f, 0.f};
        float4 s1 = {0.f, 0.f, 0.f, 0.f};
        #pragma unroll
        for (int j = 0; j < MAX_NB; ++j) {
            const float* q0 = ptr_s[r0][j];
            const float* q1 = ptr_s[r0 + 32][j];
            const float4 v0 = *(const float4*)(q0 + k0 + kq);
            const float4 v1 = *(const float4*)(q1 + k0 + kq);
            s0.x += v0.x; s0.y += v0.y; s0.z += v0.z; s0.w += v0.w;
            s1.x += v1.x; s1.y += v1.y; s1.z += v1.z; s1.w += v1.w;
        }
        As[kq + 0][r0] = s0.x; As[kq + 1][r0] = s0.y;
        As[kq + 2][r0] = s0.z; As[kq + 3][r0] = s0.w;
        As[kq + 0][r0 + 32] = s1.x; As[kq + 1][r0 + 32] = s1.y;
        As[kq + 2][r0 + 32] = s1.z; As[kq + 3][r0 + 32] = s1.w;
        // B-tile
        #pragma unroll
        for (int i = 0; i < 4; ++i) {
            const int idx = tid + i * 256;
            const int kk = idx >> 5;
            const int c = (idx & 31) << 2;
            *(float4*)&Bs[kk][c] = *(const float4*)(Wh + (size_t)(k0 + kk) * HD + colBase + c);
        }
        __syncthreads();
        #pragma unroll
        for (int kk = 0; kk < BK; ++kk) {
            const float4 a  = *(const float4*)&As[kk][ty * 4];
            const float4 b0 = *(const float4*)&Bs[kk][tx * 4];
            const float4 b1 = *(const float4*)&Bs[kk][64 + tx * 4];
            const float av[4] = {a.x, a.y, a.z, a.w};
            const float bv[8] = {b0.x, b0.y, b0.z, b0.w, b1.x, b1.y, b1.z, b1.w};
            #pragma unroll
            for (int i = 0; i < 4; ++i)
                #pragma unroll
                for (int j = 0; j < 8; ++j)
                    acc[i][j] += av[i] * bv[j];
        }
        __syncthreads();
    }

    // epilogue: acc += fbonds_row @ W_i (binput recompute), relu, store
    #pragma unroll
    for (int i = 0; i < 4; ++i) {
        const int r = rowBase + ty * 4 + i;
        const float* fr = fbonds + (size_t)r * FB_DIM;
        #pragma unroll
        for (int q = 0; q < FB_DIM / 4; ++q) {
            const float4 fv = *(const float4*)(fr + q * 4);
            const float fa[4] = {fv.x, fv.y, fv.z, fv.w};
            #pragma unroll
            for (int t = 0; t < 4; ++t) {
                const int k = q * 4 + t;
                const float4 b0 = *(const float4*)&wi_s[k][tx * 4];
                const float4 b1 = *(const float4*)&wi_s[k][64 + tx * 4];
                acc[i][0] += fa[t] * b0.x; acc[i][1] += fa[t] * b0.y;
                acc[i][2] += fa[t] * b0.z; acc[i][3] += fa[t] * b0.w;
                acc[i][4] += fa[t] * b1.x; acc[i][5] += fa[t] * b1.y;
                acc[i][6] += fa[t] * b1.z; acc[i][7] += fa[t] * b1.w;
            }
        }
        const size_t base = (size_t)r * HD + colBase;
        float4 o0, o1;
        o0.x = fmaxf(acc[i][0], 0.f); o0.y = fmaxf(acc[i][1], 0.f);
        o0.z = fmaxf(acc[i][2], 0.f); o0.w = fmaxf(acc[i][3], 0.f);
        o1.x = fmaxf(acc[i][4], 0.f); o1.y = fmaxf(acc[i][5], 0.f);
        o1.z = fmaxf(acc[i][6], 0.f); o1.w = fmaxf(acc[i][7], 0.f);
        *(float4*)(gdst + base + tx * 4) = o0;
        *(float4*)(gdst + base + 64 + tx * 4) = o1;
    }
}

// ------- K3: out += segsum(relu([fatoms|gather(agraph,msg)] @ W_o + b)) -------
// virtual A layout (K=320): [0,35)=fatoms, [35,40)=0, [40,296)=gather, [296,320)=0
// B rows remapped: kg<35 -> Wo[kg]; 40<=kg<296 -> Wo[kg-5]; else 0
__global__ __launch_bounds__(256)
void k_final(const int* __restrict__ agraph, const float* __restrict__ tmsg,
             const float* __restrict__ fatoms, const float* __restrict__ Wo,
             const float* __restrict__ bias, const int* __restrict__ scope,
             float* __restrict__ outsum)
{
    const float* gm = g_msg0;
    __shared__ float As[BK][BM + 4];
    __shared__ float Bs[BK][BN + 4];
    __shared__ const float* ptr_s[BM][MAX_NB];  // 5 KB
    const int tid = threadIdx.x;
    const int rowBase = blockIdx.x * BM;
    const int colBase = blockIdx.y * BN;

    for (int idx = tid; idx < BM * MAX_NB; idx += 256) {
        const int r = idx / MAX_NB;
        const int j = idx - r * MAX_NB;
        const int ra = rowBase + r;
        const int id = (ra < A_N) ? agraph[(size_t)ra * MAX_NB + j] : 0;  // tmsg[0]=0 pad
        ptr_s[r][j] = (id < M_N) ? (tmsg + (size_t)id * HD)
                                 : (gm + (size_t)(id - M_N) * HD);
    }
    __syncthreads();

    const int r0 = tid >> 3;
    const int kq = (tid & 7) << 2;
    const int ra0 = rowBase + r0;
    const int ra1 = rowBase + r0 + 32;
    const bool v0 = ra0 < A_N;
    const bool v1 = ra1 < A_N;
    const int tx = tid & 15;
    const int ty = tid >> 4;
    float acc[4][8] = {};

    for (int k0 = 0; k0 < 320; k0 += BK) {
        const int k = k0 + kq;
        float4 s0 = {0.f, 0.f, 0.f, 0.f};
        float4 s1 = {0.f, 0.f, 0.f, 0.f};
        if (k >= 40 && k < 296) {
            const int off = k - 40;
            #pragma unroll
            for (int j = 0; j < MAX_NB; ++j) {
                const float4 va = *(const float4*)(ptr_s[r0][j] + off);
                const float4 vb = *(const float4*)(ptr_s[r0 + 32][j] + off);
                s0.x += va.x; s0.y += va.y; s0.z += va.z; s0.w += va.w;
                s1.x += vb.x; s1.y += vb.y; s1.z += vb.z; s1.w += vb.w;
            }
        } else if (k < 40) {
            #pragma unroll
            for (int q = 0; q < 4; ++q) {
                const int kk = k + q;
                float x0 = 0.f, x1 = 0.f;
                if (kk < ATOM_FDIM) {
                    if (v0) x0 = fatoms[(size_t)ra0 * ATOM_FDIM + kk];
                    if (v1) x1 = fatoms[(size_t)ra1 * ATOM_FDIM + kk];
                }
                ((float*)&s0)[q] = x0;
                ((float*)&s1)[q] = x1;
            }
        }
        As[kq + 0][r0] = s0.x; As[kq + 1][r0] = s0.y;
        As[kq + 2][r0] = s0.z; As[kq + 3][r0] = s0.w;
        As[kq + 0][r0 + 32] = s1.x; As[kq + 1][r0 + 32] = s1.y;
        As[kq + 2][r0 + 32] = s1.z; As[kq + 3][r0 + 32] = s1.w;
        #pragma unroll
        for (int i = 0; i < 4; ++i) {
            const int idx = tid + i * 256;
            const int kk = idx >> 5;
            const int c = (idx & 31) << 2;
            const int kg = k0 + kk;
            float4 v = {0.f, 0.f, 0.f, 0.f};
            if (kg < ATOM_FDIM)
                v = *(const float4*)(Wo + (size_t)kg * HD + colBase + c);
            else if (kg >= 40 && kg < 296)
                v = *(const float4*)(Wo + (size_t)(kg - 5) * HD + colBase + c);
            *(float4*)&Bs[kk][c] = v;
        }
        __syncthreads();
        #pragma unroll
        for (int kk = 0; kk < BK; ++kk) {
            const float4 a  = *(const float4*)&As[kk][ty * 4];
            const float4 b0 = *(const float4*)&Bs[kk][tx * 4];
            const float4 b1 = *(const float4*)&Bs[kk][64 + tx * 4];
            const float av[4] = {a.x, a.y, a.z, a.w};
            const float bv[8] = {b0.x, b0.y, b0.z, b0.w, b1.x, b1.y, b1.z, b1.w};
            #pragma unroll
            for (int i = 0; i < 4; ++i)
                #pragma unroll
                for (int j = 0; j < 8; ++j)
                    acc[i][j] += av[i] * bv[j];
        }
        __syncthreads();
    }

    const float4 bb0 = *(const float4*)(bias + colBase + tx * 4);
    const float4 bb1 = *(const float4*)(bias + colBase + 64 + tx * 4);
    const float bb[8] = {bb0.x, bb0.y, bb0.z, bb0.w, bb1.x, bb1.y, bb1.z, bb1.w};
    float s[8] = {0.f, 0.f, 0.f, 0.f, 0.f, 0.f, 0.f, 0.f};
    int prev = -1;
    #pragma unroll
    for (int i = 0; i < 4; ++i) {
        const int r = rowBase + ty * 4 + i;
        if (r < A_N) {
            const int m = scope[r];
            if (m != prev) {
                if (prev >= 0) {
                    float* dst = outsum + (size_t)prev * HD + colBase;
                    #pragma unroll
                    for (int q = 0; q < 4; ++q) {
                        atomicAdd(dst + tx * 4 + q, s[q]);
                        atomicAdd(dst + 64 + tx * 4 + q, s[4 + q]);
                    }
                    #pragma unroll
                    for (int q = 0; q < 8; ++q) s[q] = 0.f;
                }
                prev = m;
            }
            #pragma unroll
            for (int q = 0; q < 8; ++q)
                s[q] += fmaxf(acc[i][q] + bb[q], 0.f);
        }
    }
    if (prev >= 0) {
        float* dst = outsum + (size_t)prev * HD + colBase;
        #pragma unroll
        for (int q = 0; q < 4; ++q) {
            atomicAdd(dst + tx * 4 + q, s[q]);
            atomicAdd(dst + 64 + tx * 4 + q, s[4 + q]);
        }
    }
}

// ---------------- counts + divide ----------------
__global__ __launch_bounds__(256)
void k_counts(const int* __restrict__ scope)
{
    const int a = blockIdx.x * 256 + threadIdx.x;
    if (a < A_N) atomicAdd(&g_counts[scope[a]], 1.0f);
}

__global__ __launch_bounds__(256)
void k_div(float* __restrict__ out)
{
    const int idx = blockIdx.x * 256 + threadIdx.x;
    out[idx] = out[idx] / fmaxf(g_counts[idx >> 8], 1.0f);
}

// ---------------- launch ----------------
extern "C" void kernel_launch(void* const* d_in, const int* in_sizes, int n_in,
                              void* d_out, int out_size, void* d_ws, size_t ws_size,
                              hipStream_t stream)
{
    const float* fatoms = (const float*)d_in[0];
    const float* fbonds = (const float*)d_in[1];
    const int*   agraph = (const int*)d_in[2];
    const int*   bgraph = (const int*)d_in[3];
    const float* tmsg   = (const float*)d_in[4];
    const int*   scope  = (const int*)d_in[5];
    const float* W_i    = (const float*)d_in[6];
    const float* W_h    = (const float*)d_in[7];
    const float* W_o    = (const float*)d_in[8];
    const float* W_ob   = (const float*)d_in[9];
    float* out = (float*)d_out;

    (void)d_ws; (void)ws_size;

    k_zero_out<<<(N_MOLS * HD + 255) / 256, 256, 0, stream>>>(out, N_MOLS * HD);
    k_zero_counts<<<(N_MOLS + 255) / 256, 256, 0, stream>>>();

    k_in<<<4096, 256, 0, stream>>>(fbonds, W_i);
    k_mp<<<dim3(B_N / BM, HD / BN), 256, 0, stream>>>(bgraph, tmsg, W_h, fbonds, W_i, 0);
    k_mp<<<dim3(B_N / BM, HD / BN), 256, 0, stream>>>(bgraph, tmsg, W_h, fbonds, W_i, 1);
    k_counts<<<(A_N + 255) / 256, 256, 0, stream>>>(scope);
    k_final<<<dim3((A_N + BM - 1) / BM, HD / BN), 256, 0, stream>>>(agraph, tmsg, fatoms, W_o, W_ob, scope, out);
    k_div<<<(N_MOLS * HD) / 256, 256, 0, stream>>>(out);
}

// Round 5
// 5348.563 us; speedup vs baseline: 1.3487x; 1.3487x over previous
//
#include <hip/hip_runtime.h>
#include <cstdint>
#include <cstddef>

#define A_N 100000
#define B_N 200000
#define M_N 20000
#define HD 256
#define MAX_NB 10
#define N_MOLS 2000
#define ATOM_FDIM 35
#define FB_DIM 40

#define BM 64
#define BN 128
#define BK 32

// Static device buffers — no assumptions about ws_size.
__device__ float g_msg0[(size_t)B_N * HD];
__device__ float g_msg1[(size_t)B_N * HD];
__device__ float g_counts[N_MOLS];

// ---------------- zero fill ----------------
__global__ __launch_bounds__(256)
void k_zero_out(float* __restrict__ p, int n)
{
    const int i = blockIdx.x * 256 + threadIdx.x;
    if (i < n) p[i] = 0.f;
}

__global__ __launch_bounds__(256)
void k_zero_counts()
{
    const int i = blockIdx.x * 256 + threadIdx.x;
    if (i < N_MOLS) g_counts[i] = 0.f;
}

// ---------------- K1: g_msg0 = relu(fbonds @ W_i) ----------------
__global__ __launch_bounds__(256)
void k_in(const float* __restrict__ fbonds, const float* __restrict__ Wi)
{
    __shared__ float Ws[FB_DIM * HD];                      // 40 KB
    for (int i = threadIdx.x; i < FB_DIM * HD; i += 256) Ws[i] = Wi[i];
    __syncthreads();
    const int lane = threadIdx.x & 63;
    const int wid  = (blockIdx.x * 256 + threadIdx.x) >> 6;
    const int nw   = (gridDim.x * 256) >> 6;
    for (int row = wid; row < B_N; row += nw) {
        const float* fr = fbonds + (size_t)row * FB_DIM;
        float ax = 0.f, ay = 0.f, az = 0.f, aw = 0.f;
        #pragma unroll
        for (int q = 0; q < FB_DIM / 4; ++q) {
            const float4 fv = *(const float4*)(fr + q * 4);
            const float fa[4] = {fv.x, fv.y, fv.z, fv.w};
            #pragma unroll
            for (int t = 0; t < 4; ++t) {
                const float4 w = *(const float4*)&Ws[(q * 4 + t) * HD + lane * 4];
                ax += fa[t] * w.x; ay += fa[t] * w.y;
                az += fa[t] * w.z; aw += fa[t] * w.w;
            }
        }
        float4 r; r.x = fmaxf(ax, 0.f); r.y = fmaxf(ay, 0.f);
        r.z = fmaxf(az, 0.f); r.w = fmaxf(aw, 0.f);
        *(float4*)(g_msg0 + (size_t)row * HD + lane * 4) = r;
    }
}

// ------- K2 (x2): dst = relu(fbonds@W_i + gather(bgraph,[tmsg;src]) @ W_h) -------
// R4 post-mortem: full unroll of the BK=32 kk-loop batched ~96 ds_read_b128
// (~384 VGPRs demand) -> allocator capped at 256 and spilled acc every k0 iter
// (2.44 GB/dispatch scratch writes). Fix: unroll 4 on kk, unroll 1 on k0,
// launch_bounds(256,3) to cap VGPR ~160 (= LDS-limited 3 blocks/CU anyway).
__global__ __launch_bounds__(256, 3)
void k_mp(const int* __restrict__ bgraph, const float* __restrict__ tmsg,
          const float* __restrict__ Wh, const float* __restrict__ fbonds,
          const float* __restrict__ Wi, int srcSel)
{
    const float* gsrc = srcSel ? g_msg1 : g_msg0;
    float* gdst       = srcSel ? g_msg0 : g_msg1;

    __shared__ float As[BK][BM + 4];            // 8.5 KB
    __shared__ float Bs[BK][BN + 4];            // 16.5 KB
    __shared__ float wi_s[FB_DIM][BN];          // 20 KB
    __shared__ const float* ptr_s[BM][MAX_NB];  // 5 KB
    const int tid = threadIdx.x;
    const int rowBase = blockIdx.x * BM;
    const int colBase = blockIdx.y * BN;

    for (int idx = tid; idx < BM * MAX_NB; idx += 256) {
        const int r = idx / MAX_NB;
        const int j = idx - r * MAX_NB;
        const int id = bgraph[(size_t)(rowBase + r) * MAX_NB + j];
        ptr_s[r][j] = (id < M_N) ? (tmsg + (size_t)id * HD)
                                 : (gsrc + (size_t)(id - M_N) * HD);
    }
    #pragma unroll
    for (int i = 0; i < 5; ++i) {
        const int idx = tid + i * 256;
        const int k = idx >> 5;
        const int c = (idx & 31) << 2;
        *(float4*)&wi_s[k][c] = *(const float4*)(Wi + (size_t)k * HD + colBase + c);
    }
    __syncthreads();

    const int r0 = tid >> 3;               // [0,32)
    const int kq = (tid & 7) << 2;         // {0,4,...,28}
    const int tx = tid & 15;
    const int ty = tid >> 4;
    float acc[4][8] = {};

    #pragma unroll 1
    for (int k0 = 0; k0 < HD; k0 += BK) {
        // A-tile: gather-sum of 10 neighbor rows (pointers from LDS)
        float4 s0 = {0.f, 0.f, 0.f, 0.f};
        float4 s1 = {0.f, 0.f, 0.f, 0.f};
        #pragma unroll
        for (int j = 0; j < MAX_NB; ++j) {
            const float* q0 = ptr_s[r0][j];
            const float* q1 = ptr_s[r0 + 32][j];
            const float4 v0 = *(const float4*)(q0 + k0 + kq);
            const float4 v1 = *(const float4*)(q1 + k0 + kq);
            s0.x += v0.x; s0.y += v0.y; s0.z += v0.z; s0.w += v0.w;
            s1.x += v1.x; s1.y += v1.y; s1.z += v1.z; s1.w += v1.w;
        }
        As[kq + 0][r0] = s0.x; As[kq + 1][r0] = s0.y;
        As[kq + 2][r0] = s0.z; As[kq + 3][r0] = s0.w;
        As[kq + 0][r0 + 32] = s1.x; As[kq + 1][r0 + 32] = s1.y;
        As[kq + 2][r0 + 32] = s1.z; As[kq + 3][r0 + 32] = s1.w;
        // B-tile
        #pragma unroll
        for (int i = 0; i < 4; ++i) {
            const int idx = tid + i * 256;
            const int kk = idx >> 5;
            const int c = (idx & 31) << 2;
            *(float4*)&Bs[kk][c] = *(const float4*)(Wh + (size_t)(k0 + kk) * HD + colBase + c);
        }
        __syncthreads();
        #pragma unroll 4
        for (int kk = 0; kk < BK; ++kk) {
            const float4 a  = *(const float4*)&As[kk][ty * 4];
            const float4 b0 = *(const float4*)&Bs[kk][tx * 4];
            const float4 b1 = *(const float4*)&Bs[kk][64 + tx * 4];
            const float av[4] = {a.x, a.y, a.z, a.w};
            const float bv[8] = {b0.x, b0.y, b0.z, b0.w, b1.x, b1.y, b1.z, b1.w};
            #pragma unroll
            for (int i = 0; i < 4; ++i)
                #pragma unroll
                for (int j = 0; j < 8; ++j)
                    acc[i][j] += av[i] * bv[j];
        }
        __syncthreads();
    }

    // epilogue: acc += fbonds_row @ W_i (binput recompute), relu, store
    #pragma unroll 1
    for (int i = 0; i < 4; ++i) {
        const int r = rowBase + ty * 4 + i;
        const float* fr = fbonds + (size_t)r * FB_DIM;
        #pragma unroll
        for (int q = 0; q < FB_DIM / 4; ++q) {
            const float4 fv = *(const float4*)(fr + q * 4);
            const float fa[4] = {fv.x, fv.y, fv.z, fv.w};
            #pragma unroll
            for (int t = 0; t < 4; ++t) {
                const int k = q * 4 + t;
                const float4 b0 = *(const float4*)&wi_s[k][tx * 4];
                const float4 b1 = *(const float4*)&wi_s[k][64 + tx * 4];
                acc[i][0] += fa[t] * b0.x; acc[i][1] += fa[t] * b0.y;
                acc[i][2] += fa[t] * b0.z; acc[i][3] += fa[t] * b0.w;
                acc[i][4] += fa[t] * b1.x; acc[i][5] += fa[t] * b1.y;
                acc[i][6] += fa[t] * b1.z; acc[i][7] += fa[t] * b1.w;
            }
        }
        const size_t base = (size_t)r * HD + colBase;
        float4 o0, o1;
        o0.x = fmaxf(acc[i][0], 0.f); o0.y = fmaxf(acc[i][1], 0.f);
        o0.z = fmaxf(acc[i][2], 0.f); o0.w = fmaxf(acc[i][3], 0.f);
        o1.x = fmaxf(acc[i][4], 0.f); o1.y = fmaxf(acc[i][5], 0.f);
        o1.z = fmaxf(acc[i][6], 0.f); o1.w = fmaxf(acc[i][7], 0.f);
        *(float4*)(gdst + base + tx * 4) = o0;
        *(float4*)(gdst + base + 64 + tx * 4) = o1;
    }
}

// ------- K3: out += segsum(relu([fatoms|gather(agraph,msg)] @ W_o + b)) -------
// virtual A layout (K=320): [0,35)=fatoms, [35,40)=0, [40,296)=gather, [296,320)=0
// B rows remapped: kg<35 -> Wo[kg]; 40<=kg<296 -> Wo[kg-5]; else 0
__global__ __launch_bounds__(256, 3)
void k_final(const int* __restrict__ agraph, const float* __restrict__ tmsg,
             const float* __restrict__ fatoms, const float* __restrict__ Wo,
             const float* __restrict__ bias, const int* __restrict__ scope,
             float* __restrict__ outsum)
{
    const float* gm = g_msg0;
    __shared__ float As[BK][BM + 4];
    __shared__ float Bs[BK][BN + 4];
    __shared__ const float* ptr_s[BM][MAX_NB];  // 5 KB
    const int tid = threadIdx.x;
    const int rowBase = blockIdx.x * BM;
    const int colBase = blockIdx.y * BN;

    for (int idx = tid; idx < BM * MAX_NB; idx += 256) {
        const int r = idx / MAX_NB;
        const int j = idx - r * MAX_NB;
        const int ra = rowBase + r;
        const int id = (ra < A_N) ? agraph[(size_t)ra * MAX_NB + j] : 0;  // tmsg[0]=0 pad
        ptr_s[r][j] = (id < M_N) ? (tmsg + (size_t)id * HD)
                                 : (gm + (size_t)(id - M_N) * HD);
    }
    __syncthreads();

    const int r0 = tid >> 3;
    const int kq = (tid & 7) << 2;
    const int ra0 = rowBase + r0;
    const int ra1 = rowBase + r0 + 32;
    const bool v0 = ra0 < A_N;
    const bool v1 = ra1 < A_N;
    const int tx = tid & 15;
    const int ty = tid >> 4;
    float acc[4][8] = {};

    #pragma unroll 1
    for (int k0 = 0; k0 < 320; k0 += BK) {
        const int k = k0 + kq;
        float4 s0 = {0.f, 0.f, 0.f, 0.f};
        float4 s1 = {0.f, 0.f, 0.f, 0.f};
        if (k >= 40 && k < 296) {
            const int off = k - 40;
            #pragma unroll
            for (int j = 0; j < MAX_NB; ++j) {
                const float4 va = *(const float4*)(ptr_s[r0][j] + off);
                const float4 vb = *(const float4*)(ptr_s[r0 + 32][j] + off);
                s0.x += va.x; s0.y += va.y; s0.z += va.z; s0.w += va.w;
                s1.x += vb.x; s1.y += vb.y; s1.z += vb.z; s1.w += vb.w;
            }
        } else if (k < 40) {
            #pragma unroll
            for (int q = 0; q < 4; ++q) {
                const int kk = k + q;
                float x0 = 0.f, x1 = 0.f;
                if (kk < ATOM_FDIM) {
                    if (v0) x0 = fatoms[(size_t)ra0 * ATOM_FDIM + kk];
                    if (v1) x1 = fatoms[(size_t)ra1 * ATOM_FDIM + kk];
                }
                ((float*)&s0)[q] = x0;
                ((float*)&s1)[q] = x1;
            }
        }
        As[kq + 0][r0] = s0.x; As[kq + 1][r0] = s0.y;
        As[kq + 2][r0] = s0.z; As[kq + 3][r0] = s0.w;
        As[kq + 0][r0 + 32] = s1.x; As[kq + 1][r0 + 32] = s1.y;
        As[kq + 2][r0 + 32] = s1.z; As[kq + 3][r0 + 32] = s1.w;
        #pragma unroll
        for (int i = 0; i < 4; ++i) {
            const int idx = tid + i * 256;
            const int kk = idx >> 5;
            const int c = (idx & 31) << 2;
            const int kg = k0 + kk;
            float4 v = {0.f, 0.f, 0.f, 0.f};
            if (kg < ATOM_FDIM)
                v = *(const float4*)(Wo + (size_t)kg * HD + colBase + c);
            else if (kg >= 40 && kg < 296)
                v = *(const float4*)(Wo + (size_t)(kg - 5) * HD + colBase + c);
            *(float4*)&Bs[kk][c] = v;
        }
        __syncthreads();
        #pragma unroll 4
        for (int kk = 0; kk < BK; ++kk) {
            const float4 a  = *(const float4*)&As[kk][ty * 4];
            const float4 b0 = *(const float4*)&Bs[kk][tx * 4];
            const float4 b1 = *(const float4*)&Bs[kk][64 + tx * 4];
            const float av[4] = {a.x, a.y, a.z, a.w};
            const float bv[8] = {b0.x, b0.y, b0.z, b0.w, b1.x, b1.y, b1.z, b1.w};
            #pragma unroll
            for (int i = 0; i < 4; ++i)
                #pragma unroll
                for (int j = 0; j < 8; ++j)
                    acc[i][j] += av[i] * bv[j];
        }
        __syncthreads();
    }

    const float4 bb0 = *(const float4*)(bias + colBase + tx * 4);
    const float4 bb1 = *(const float4*)(bias + colBase + 64 + tx * 4);
    const float bb[8] = {bb0.x, bb0.y, bb0.z, bb0.w, bb1.x, bb1.y, bb1.z, bb1.w};
    float s[8] = {0.f, 0.f, 0.f, 0.f, 0.f, 0.f, 0.f, 0.f};
    int prev = -1;
    #pragma unroll
    for (int i = 0; i < 4; ++i) {
        const int r = rowBase + ty * 4 + i;
        if (r < A_N) {
            const int m = scope[r];
            if (m != prev) {
                if (prev >= 0) {
                    float* dst = outsum + (size_t)prev * HD + colBase;
                    #pragma unroll
                    for (int q = 0; q < 4; ++q) {
                        atomicAdd(dst + tx * 4 + q, s[q]);
                        atomicAdd(dst + 64 + tx * 4 + q, s[4 + q]);
                    }
                    #pragma unroll
                    for (int q = 0; q < 8; ++q) s[q] = 0.f;
                }
                prev = m;
            }
            #pragma unroll
            for (int q = 0; q < 8; ++q)
                s[q] += fmaxf(acc[i][q] + bb[q], 0.f);
        }
    }
    if (prev >= 0) {
        float* dst = outsum + (size_t)prev * HD + colBase;
        #pragma unroll
        for (int q = 0; q < 4; ++q) {
            atomicAdd(dst + tx * 4 + q, s[q]);
            atomicAdd(dst + 64 + tx * 4 + q, s[4 + q]);
        }
    }
}

// ---------------- counts + divide ----------------
__global__ __launch_bounds__(256)
void k_counts(const int* __restrict__ scope)
{
    const int a = blockIdx.x * 256 + threadIdx.x;
    if (a < A_N) atomicAdd(&g_counts[scope[a]], 1.0f);
}

__global__ __launch_bounds__(256)
void k_div(float* __restrict__ out)
{
    const int idx = blockIdx.x * 256 + threadIdx.x;
    out[idx] = out[idx] / fmaxf(g_counts[idx >> 8], 1.0f);
}

// ---------------- launch ----------------
extern "C" void kernel_launch(void* const* d_in, const int* in_sizes, int n_in,
                              void* d_out, int out_size, void* d_ws, size_t ws_size,
                              hipStream_t stream)
{
    const float* fatoms = (const float*)d_in[0];
    const float* fbonds = (const float*)d_in[1];
    const int*   agraph = (const int*)d_in[2];
    const int*   bgraph = (const int*)d_in[3];
    const float* tmsg   = (const float*)d_in[4];
    const int*   scope  = (const int*)d_in[5];
    const float* W_i    = (const float*)d_in[6];
    const float* W_h    = (const float*)d_in[7];
    const float* W_o    = (const float*)d_in[8];
    const float* W_ob   = (const float*)d_in[9];
    float* out = (float*)d_out;

    (void)d_ws; (void)ws_size;

    k_zero_out<<<(N_MOLS * HD + 255) / 256, 256, 0, stream>>>(out, N_MOLS * HD);
    k_zero_counts<<<(N_MOLS + 255) / 256, 256, 0, stream>>>();

    k_in<<<4096, 256, 0, stream>>>(fbonds, W_i);
    k_mp<<<dim3(B_N / BM, HD / BN), 256, 0, stream>>>(bgraph, tmsg, W_h, fbonds, W_i, 0);
    k_mp<<<dim3(B_N / BM, HD / BN), 256, 0, stream>>>(bgraph, tmsg, W_h, fbonds, W_i, 1);
    k_counts<<<(A_N + 255) / 256, 256, 0, stream>>>(scope);
    k_final<<<dim3((A_N + BM - 1) / BM, HD / BN), 256, 0, stream>>>(agraph, tmsg, fatoms, W_o, W_ob, scope, out);
    k_div<<<(N_MOLS * HD) / 256, 256, 0, stream>>>(out);
}

// Round 6
// 5110.052 us; speedup vs baseline: 1.4116x; 1.0467x over previous
//
#include <hip/hip_runtime.h>
#include <cstdint>
#include <cstddef>

#define A_N 100000
#define B_N 200000
#define M_N 20000
#define HD 256
#define MAX_NB 10
#define N_MOLS 2000
#define ATOM_FDIM 35
#define FB_DIM 40

#define BM 64
#define BK 32
#define BN 256   // full width — one block covers all columns (gather done once)

typedef unsigned short u16;

// Static device buffers. Messages stored bf16 (raw u16): pool = 2*102.4 + 10.2 MB.
__device__ u16 g_msg0[(size_t)B_N * HD];
__device__ u16 g_msg1[(size_t)B_N * HD];
__device__ u16 g_tmsgh[(size_t)M_N * HD];
__device__ float g_counts[N_MOLS];

// fp32 -> bf16 round-to-nearest-even (inputs are finite; no NaN handling needed)
__device__ __forceinline__ u16 f2b(float f)
{
    union { float f; unsigned u; } x; x.f = f;
    const unsigned r = x.u + 0x7FFFu + ((x.u >> 16) & 1u);
    return (u16)(r >> 16);
}

// ---------------- zero fill ----------------
__global__ __launch_bounds__(256)
void k_zero_out(float* __restrict__ p, int n)
{
    const int i = blockIdx.x * 256 + threadIdx.x;
    if (i < n) p[i] = 0.f;
}

__global__ __launch_bounds__(256)
void k_zero_counts()
{
    const int i = blockIdx.x * 256 + threadIdx.x;
    if (i < N_MOLS) g_counts[i] = 0.f;
}

// ---------------- tmsg fp32 -> bf16 ----------------
__global__ __launch_bounds__(256)
void k_cvt(const float* __restrict__ tmsg)
{
    const int i = (blockIdx.x * 256 + threadIdx.x) * 4;
    if (i < M_N * HD) {
        const float4 v = *(const float4*)(tmsg + i);
        ushort4 o;
        o.x = f2b(v.x); o.y = f2b(v.y); o.z = f2b(v.z); o.w = f2b(v.w);
        *(ushort4*)(g_tmsgh + i) = o;
    }
}

// ---------------- K1: g_msg0 = bf16(relu(fbonds @ W_i)) ----------------
__global__ __launch_bounds__(256)
void k_in(const float* __restrict__ fbonds, const float* __restrict__ Wi)
{
    __shared__ float Ws[FB_DIM * HD];                      // 40 KB
    for (int i = threadIdx.x; i < FB_DIM * HD; i += 256) Ws[i] = Wi[i];
    __syncthreads();
    const int lane = threadIdx.x & 63;
    const int wid  = (blockIdx.x * 256 + threadIdx.x) >> 6;
    const int nw   = (gridDim.x * 256) >> 6;
    for (int row = wid; row < B_N; row += nw) {
        const float* fr = fbonds + (size_t)row * FB_DIM;
        float ax = 0.f, ay = 0.f, az = 0.f, aw = 0.f;
        #pragma unroll
        for (int q = 0; q < FB_DIM / 4; ++q) {
            const float4 fv = *(const float4*)(fr + q * 4);
            const float fa[4] = {fv.x, fv.y, fv.z, fv.w};
            #pragma unroll
            for (int t = 0; t < 4; ++t) {
                const float4 w = *(const float4*)&Ws[(q * 4 + t) * HD + lane * 4];
                ax += fa[t] * w.x; ay += fa[t] * w.y;
                az += fa[t] * w.z; aw += fa[t] * w.w;
            }
        }
        ushort4 o;
        o.x = f2b(fmaxf(ax, 0.f)); o.y = f2b(fmaxf(ay, 0.f));
        o.z = f2b(fmaxf(az, 0.f)); o.w = f2b(fmaxf(aw, 0.f));
        *(ushort4*)(g_msg0 + (size_t)row * HD + lane * 4) = o;
    }
}

// ------- K2 (x2): dst = bf16(relu(fbonds@W_i + gather(bgraph,[tmsg;src]) @ W_h)) -------
// One block = 64 rows x ALL 256 cols -> each gather row fetched once (was 2x).
// Messages bf16 in HBM; all LDS tiles / accumulation fp32.
__global__ __launch_bounds__(256, 3)
void k_mp(const int* __restrict__ bgraph, const float* __restrict__ Wh,
          const float* __restrict__ fbonds, const float* __restrict__ Wi,
          int srcSel)
{
    const u16* gsrc = srcSel ? g_msg1 : g_msg0;
    u16* gdst       = srcSel ? g_msg0 : g_msg1;

    __shared__ float As[BK][BM + 4];            // 8.7 KB
    __shared__ float Bs[BK][BN + 4];            // 33.3 KB (reused as wi tile in epilogue)
    __shared__ const u16* ptr_s[BM][MAX_NB];    // 5 KB
    float (*wi_s)[132] = (float(*)[132])Bs;     // 40x132 = 21 KB overlay

    const int tid = threadIdx.x;
    const int rowBase = blockIdx.x * BM;

    for (int idx = tid; idx < BM * MAX_NB; idx += 256) {
        const int r = idx / MAX_NB;
        const int j = idx - r * MAX_NB;
        const int id = bgraph[(size_t)(rowBase + r) * MAX_NB + j];
        ptr_s[r][j] = (id < M_N) ? (g_tmsgh + (size_t)id * HD)
                                 : (gsrc + (size_t)(id - M_N) * HD);
    }
    __syncthreads();

    const int r   = tid >> 2;              // [0,64) gather row
    const int kq8 = (tid & 3) << 3;        // {0,8,16,24}
    const int tx = tid & 15;
    const int ty = tid >> 4;
    float acc[4][16] = {};

    #pragma unroll 1
    for (int k0 = 0; k0 < HD; k0 += BK) {
        // A-tile: gather-sum of 10 bf16 rows (8 bf16 = 16 B per lane)
        float s[8] = {0.f,0.f,0.f,0.f,0.f,0.f,0.f,0.f};
        #pragma unroll
        for (int j = 0; j < MAX_NB; ++j) {
            const uint4 v = *(const uint4*)(ptr_s[r][j] + k0 + kq8);
            s[0] += __uint_as_float(v.x << 16);
            s[1] += __uint_as_float(v.x & 0xffff0000u);
            s[2] += __uint_as_float(v.y << 16);
            s[3] += __uint_as_float(v.y & 0xffff0000u);
            s[4] += __uint_as_float(v.z << 16);
            s[5] += __uint_as_float(v.z & 0xffff0000u);
            s[6] += __uint_as_float(v.w << 16);
            s[7] += __uint_as_float(v.w & 0xffff0000u);
        }
        #pragma unroll
        for (int t = 0; t < 8; ++t) As[kq8 + t][r] = s[t];
        // B-tile: 32x256 fp32, 8 float4 per thread
        #pragma unroll
        for (int i = 0; i < 8; ++i) {
            const int idx = tid + i * 256;
            const int kk = idx >> 6;
            const int c4 = (idx & 63) << 2;
            *(float4*)&Bs[kk][c4] = *(const float4*)(Wh + (size_t)(k0 + kk) * HD + c4);
        }
        __syncthreads();
        #pragma unroll 4
        for (int kk = 0; kk < BK; ++kk) {
            const float4 a = *(const float4*)&As[kk][ty * 4];
            const float av[4] = {a.x, a.y, a.z, a.w};
            #pragma unroll
            for (int g = 0; g < 4; ++g) {
                const float4 b = *(const float4*)&Bs[kk][g * 64 + tx * 4];
                const float bv[4] = {b.x, b.y, b.z, b.w};
                #pragma unroll
                for (int i = 0; i < 4; ++i)
                    #pragma unroll
                    for (int q = 0; q < 4; ++q)
                        acc[i][g * 4 + q] += av[i] * bv[q];
            }
        }
        __syncthreads();
    }

    // epilogue per 128-col half: reload W_i tile into Bs overlay, add binput, relu, bf16 store
    #pragma unroll 1
    for (int h = 0; h < 2; ++h) {
        #pragma unroll
        for (int i = 0; i < 5; ++i) {
            const int idx = tid + i * 256;     // 1280 float4 slots (40 x 32)
            const int k = idx >> 5;
            const int c4 = (idx & 31) << 2;
            *(float4*)&wi_s[k][c4] = *(const float4*)(Wi + (size_t)k * HD + h * 128 + c4);
        }
        __syncthreads();
        #pragma unroll 1
        for (int i = 0; i < 4; ++i) {
            const int rr = rowBase + ty * 4 + i;
            const float* fr = fbonds + (size_t)rr * FB_DIM;
            float a0[4] = {acc[i][8*h+0], acc[i][8*h+1], acc[i][8*h+2], acc[i][8*h+3]};
            float a1[4] = {acc[i][8*h+4], acc[i][8*h+5], acc[i][8*h+6], acc[i][8*h+7]};
            #pragma unroll
            for (int q = 0; q < FB_DIM / 4; ++q) {
                const float4 fv = *(const float4*)(fr + q * 4);
                const float fa[4] = {fv.x, fv.y, fv.z, fv.w};
                #pragma unroll
                for (int t = 0; t < 4; ++t) {
                    const int k = q * 4 + t;
                    const float4 b0 = *(const float4*)&wi_s[k][tx * 4];
                    const float4 b1 = *(const float4*)&wi_s[k][64 + tx * 4];
                    a0[0] += fa[t] * b0.x; a0[1] += fa[t] * b0.y;
                    a0[2] += fa[t] * b0.z; a0[3] += fa[t] * b0.w;
                    a1[0] += fa[t] * b1.x; a1[1] += fa[t] * b1.y;
                    a1[2] += fa[t] * b1.z; a1[3] += fa[t] * b1.w;
                }
            }
            const size_t base = (size_t)rr * HD + h * 128;
            ushort4 o0, o1;
            o0.x = f2b(fmaxf(a0[0], 0.f)); o0.y = f2b(fmaxf(a0[1], 0.f));
            o0.z = f2b(fmaxf(a0[2], 0.f)); o0.w = f2b(fmaxf(a0[3], 0.f));
            o1.x = f2b(fmaxf(a1[0], 0.f)); o1.y = f2b(fmaxf(a1[1], 0.f));
            o1.z = f2b(fmaxf(a1[2], 0.f)); o1.w = f2b(fmaxf(a1[3], 0.f));
            *(ushort4*)(gdst + base + tx * 4) = o0;
            *(ushort4*)(gdst + base + 64 + tx * 4) = o1;
        }
        __syncthreads();
    }
}

// ------- K3: out += segsum(relu([fatoms|gather(agraph,msg)] @ W_o + b)) -------
// virtual A layout (K=320): [0,35)=fatoms, [35,40)=0, [40,296)=gather(bf16), [296,320)=0
// B rows remapped: kg<35 -> Wo[kg]; 40<=kg<296 -> Wo[kg-5]; else 0. One block = all 256 cols.
__global__ __launch_bounds__(256, 3)
void k_final(const int* __restrict__ agraph, const float* __restrict__ fatoms,
             const float* __restrict__ Wo, const float* __restrict__ bias,
             const int* __restrict__ scope, float* __restrict__ outsum)
{
    const u16* gm = g_msg0;
    __shared__ float As[BK][BM + 4];
    __shared__ float Bs[BK][BN + 4];
    __shared__ const u16* ptr_s[BM][MAX_NB];
    const int tid = threadIdx.x;
    const int rowBase = blockIdx.x * BM;

    for (int idx = tid; idx < BM * MAX_NB; idx += 256) {
        const int rr = idx / MAX_NB;
        const int j = idx - rr * MAX_NB;
        const int ra = rowBase + rr;
        const int id = (ra < A_N) ? agraph[(size_t)ra * MAX_NB + j] : 0;  // row 0 of tmsg = zeros
        ptr_s[rr][j] = (id < M_N) ? (g_tmsgh + (size_t)id * HD)
                                  : (gm + (size_t)(id - M_N) * HD);
    }
    __syncthreads();

    const int r   = tid >> 2;
    const int kq8 = (tid & 3) << 3;
    const int ra  = rowBase + r;
    const bool va = ra < A_N;
    const int tx = tid & 15;
    const int ty = tid >> 4;
    float acc[4][16] = {};

    #pragma unroll 1
    for (int k0 = 0; k0 < 320; k0 += BK) {
        const int k = k0 + kq8;
        if (k >= 40 && k < 296) {
            const int off = k - 40;
            float s[8] = {0.f,0.f,0.f,0.f,0.f,0.f,0.f,0.f};
            #pragma unroll
            for (int j = 0; j < MAX_NB; ++j) {
                const uint4 v = *(const uint4*)(ptr_s[r][j] + off);
                s[0] += __uint_as_float(v.x << 16);
                s[1] += __uint_as_float(v.x & 0xffff0000u);
                s[2] += __uint_as_float(v.y << 16);
                s[3] += __uint_as_float(v.y & 0xffff0000u);
                s[4] += __uint_as_float(v.z << 16);
                s[5] += __uint_as_float(v.z & 0xffff0000u);
                s[6] += __uint_as_float(v.w << 16);
                s[7] += __uint_as_float(v.w & 0xffff0000u);
            }
            #pragma unroll
            for (int t = 0; t < 8; ++t) As[kq8 + t][r] = s[t];
        } else {
            #pragma unroll
            for (int t = 0; t < 8; ++t) {
                const int kk2 = k + t;
                float x = 0.f;
                if (kk2 < ATOM_FDIM && va) x = fatoms[(size_t)ra * ATOM_FDIM + kk2];
                As[kq8 + t][r] = x;
            }
        }
        #pragma unroll
        for (int i = 0; i < 8; ++i) {
            const int idx = tid + i * 256;
            const int kk = idx >> 6;
            const int c4 = (idx & 63) << 2;
            const int kg = k0 + kk;
            float4 v = {0.f, 0.f, 0.f, 0.f};
            if (kg < ATOM_FDIM)
                v = *(const float4*)(Wo + (size_t)kg * HD + c4);
            else if (kg >= 40 && kg < 296)
                v = *(const float4*)(Wo + (size_t)(kg - 5) * HD + c4);
            *(float4*)&Bs[kk][c4] = v;
        }
        __syncthreads();
        #pragma unroll 4
        for (int kk = 0; kk < BK; ++kk) {
            const float4 a = *(const float4*)&As[kk][ty * 4];
            const float av[4] = {a.x, a.y, a.z, a.w};
            #pragma unroll
            for (int g = 0; g < 4; ++g) {
                const float4 b = *(const float4*)&Bs[kk][g * 64 + tx * 4];
                const float bv[4] = {b.x, b.y, b.z, b.w};
                #pragma unroll
                for (int i = 0; i < 4; ++i)
                    #pragma unroll
                    for (int q = 0; q < 4; ++q)
                        acc[i][g * 4 + q] += av[i] * bv[q];
            }
        }
        __syncthreads();
    }

    float bb[16];
    #pragma unroll
    for (int g = 0; g < 4; ++g) {
        const float4 b = *(const float4*)(bias + g * 64 + tx * 4);
        bb[g*4+0] = b.x; bb[g*4+1] = b.y; bb[g*4+2] = b.z; bb[g*4+3] = b.w;
    }
    float s[16] = {};
    int prev = -1;
    #pragma unroll 1
    for (int i = 0; i < 4; ++i) {
        const int rr = rowBase + ty * 4 + i;
        if (rr < A_N) {
            const int m = scope[rr];
            if (m != prev) {
                if (prev >= 0) {
                    float* dst = outsum + (size_t)prev * HD;
                    #pragma unroll
                    for (int g = 0; g < 4; ++g)
                        #pragma unroll
                        for (int q = 0; q < 4; ++q)
                            atomicAdd(dst + g * 64 + tx * 4 + q, s[g * 4 + q]);
                    #pragma unroll
                    for (int q = 0; q < 16; ++q) s[q] = 0.f;
                }
                prev = m;
            }
            #pragma unroll
            for (int q = 0; q < 16; ++q)
                s[q] += fmaxf(acc[i][q] + bb[q], 0.f);
        }
    }
    if (prev >= 0) {
        float* dst = outsum + (size_t)prev * HD;
        #pragma unroll
        for (int g = 0; g < 4; ++g)
            #pragma unroll
            for (int q = 0; q < 4; ++q)
                atomicAdd(dst + g * 64 + tx * 4 + q, s[g * 4 + q]);
    }
}

// ---------------- counts + divide ----------------
__global__ __launch_bounds__(256)
void k_counts(const int* __restrict__ scope)
{
    const int a = blockIdx.x * 256 + threadIdx.x;
    if (a < A_N) atomicAdd(&g_counts[scope[a]], 1.0f);
}

__global__ __launch_bounds__(256)
void k_div(float* __restrict__ out)
{
    const int idx = blockIdx.x * 256 + threadIdx.x;
    out[idx] = out[idx] / fmaxf(g_counts[idx >> 8], 1.0f);
}

// ---------------- launch ----------------
extern "C" void kernel_launch(void* const* d_in, const int* in_sizes, int n_in,
                              void* d_out, int out_size, void* d_ws, size_t ws_size,
                              hipStream_t stream)
{
    const float* fatoms = (const float*)d_in[0];
    const float* fbonds = (const float*)d_in[1];
    const int*   agraph = (const int*)d_in[2];
    const int*   bgraph = (const int*)d_in[3];
    const float* tmsg   = (const float*)d_in[4];
    const int*   scope  = (const int*)d_in[5];
    const float* W_i    = (const float*)d_in[6];
    const float* W_h    = (const float*)d_in[7];
    const float* W_o    = (const float*)d_in[8];
    const float* W_ob   = (const float*)d_in[9];
    float* out = (float*)d_out;

    (void)d_ws; (void)ws_size;

    k_zero_out<<<(N_MOLS * HD + 255) / 256, 256, 0, stream>>>(out, N_MOLS * HD);
    k_zero_counts<<<(N_MOLS + 255) / 256, 256, 0, stream>>>();
    k_cvt<<<(M_N * HD / 4 + 255) / 256, 256, 0, stream>>>(tmsg);

    k_in<<<4096, 256, 0, stream>>>(fbonds, W_i);
    k_mp<<<B_N / BM, 256, 0, stream>>>(bgraph, W_h, fbonds, W_i, 0);
    k_mp<<<B_N / BM, 256, 0, stream>>>(bgraph, W_h, fbonds, W_i, 1);
    k_counts<<<(A_N + 255) / 256, 256, 0, stream>>>(scope);
    k_final<<<(A_N + BM - 1) / BM, 256, 0, stream>>>(agraph, fatoms, W_o, W_ob, scope, out);
    k_div<<<(N_MOLS * HD) / 256, 256, 0, stream>>>(out);
}

// Round 7
// 3291.032 us; speedup vs baseline: 2.1918x; 1.5527x over previous
//
#include <hip/hip_runtime.h>
#include <cstdint>
#include <cstddef>

#define A_N 100000
#define B_N 200000
#define M_N 20000
#define HD 256
#define MAX_NB 10
#define N_MOLS 2000
#define ATOM_FDIM 35
#define FB_DIM 40

#define BM 64

typedef unsigned short u16;

// Static device buffers. Messages stored bf16: pool = 2*102.4 + 10.2 MB.
__device__ u16 g_msg0[(size_t)B_N * HD];
__device__ u16 g_msg1[(size_t)B_N * HD];
__device__ u16 g_tmsgh[(size_t)M_N * HD];
__device__ float g_counts[N_MOLS];

__device__ __forceinline__ u16 f2b(float f)
{
    union { float f; unsigned u; } x; x.f = f;
    const unsigned r = x.u + 0x7FFFu + ((x.u >> 16) & 1u);
    return (u16)(r >> 16);
}
__device__ __forceinline__ float blo(unsigned u) { return __uint_as_float(u << 16); }
__device__ __forceinline__ float bhi(unsigned u) { return __uint_as_float(u & 0xffff0000u); }

// ---------------- zero fill / convert ----------------
__global__ __launch_bounds__(256)
void k_zero_out(float* __restrict__ p, int n)
{
    const int i = blockIdx.x * 256 + threadIdx.x;
    if (i < n) p[i] = 0.f;
}

__global__ __launch_bounds__(256)
void k_zero_counts()
{
    const int i = blockIdx.x * 256 + threadIdx.x;
    if (i < N_MOLS) g_counts[i] = 0.f;
}

__global__ __launch_bounds__(256)
void k_cvt(const float* __restrict__ tmsg)
{
    const int i = (blockIdx.x * 256 + threadIdx.x) * 4;
    if (i < M_N * HD) {
        const float4 v = *(const float4*)(tmsg + i);
        ushort4 o;
        o.x = f2b(v.x); o.y = f2b(v.y); o.z = f2b(v.z); o.w = f2b(v.w);
        *(ushort4*)(g_tmsgh + i) = o;
    }
}

// ---------------- K1: g_msg0 = bf16(relu(fbonds @ W_i)) ----------------
__global__ __launch_bounds__(256)
void k_in(const float* __restrict__ fbonds, const float* __restrict__ Wi)
{
    __shared__ float Ws[FB_DIM * HD];                      // 40 KB
    for (int i = threadIdx.x; i < FB_DIM * HD; i += 256) Ws[i] = Wi[i];
    __syncthreads();
    const int lane = threadIdx.x & 63;
    const int wid  = (blockIdx.x * 256 + threadIdx.x) >> 6;
    const int nw   = (gridDim.x * 256) >> 6;
    for (int row = wid; row < B_N; row += nw) {
        const float* fr = fbonds + (size_t)row * FB_DIM;
        float ax = 0.f, ay = 0.f, az = 0.f, aw = 0.f;
        #pragma unroll
        for (int q = 0; q < FB_DIM / 4; ++q) {
            const float4 fv = *(const float4*)(fr + q * 4);
            const float fa[4] = {fv.x, fv.y, fv.z, fv.w};
            #pragma unroll
            for (int t = 0; t < 4; ++t) {
                const float4 w = *(const float4*)&Ws[(q * 4 + t) * HD + lane * 4];
                ax += fa[t] * w.x; ay += fa[t] * w.y;
                az += fa[t] * w.z; aw += fa[t] * w.w;
            }
        }
        ushort4 o;
        o.x = f2b(fmaxf(ax, 0.f)); o.y = f2b(fmaxf(ay, 0.f));
        o.z = f2b(fmaxf(az, 0.f)); o.w = f2b(fmaxf(aw, 0.f));
        *(ushort4*)(g_msg0 + (size_t)row * HD + lane * 4) = o;
    }
}

// ------- K2 (x2): dst = bf16(relu(fbonds@W_i + gather(bgraph,[tmsg;src]) @ W_h)) -------
// R6 post-mortem: runtime-indexed acc[][] in the `unroll 1` epilogue exiled the
// accumulator to scratch -> 3.2 GB/dispatch scratch round-trips. This version:
// acc statically indexed EVERYWHERE (epilogue fully unrolled); BK=64 gather so
// 4 lanes x 2 reads cover exactly one aligned 128 B line per neighbor row slice.
__global__ __launch_bounds__(256, 2)
void k_mp(const int* __restrict__ bgraph, const float* __restrict__ Wh,
          const float* __restrict__ fbonds, const float* __restrict__ Wi,
          int srcSel)
{
    const u16* gsrc = srcSel ? g_msg1 : g_msg0;
    u16* gdst       = srcSel ? g_msg0 : g_msg1;

    __shared__ float As[64][68];                // 17.4 KB  [k][row], 64-wide K slice
    __shared__ float Bs[32][260];               // 33.3 KB  32-row half-slice of Wh
    __shared__ const u16* ptr_s[BM][MAX_NB];    // 5 KB
    float (*wi_s)[132] = (float(*)[132])Bs;     // 40x132 = 21.1 KB overlay (epilogue)
    float (*fb_s)[44]  = (float(*)[44])As;      // 64x44  = 11.3 KB overlay (epilogue)

    const int tid = threadIdx.x;
    const int rowBase = blockIdx.x * BM;

    for (int idx = tid; idx < BM * MAX_NB; idx += 256) {
        const int r = idx / MAX_NB;
        const int j = idx - r * MAX_NB;
        const int id = bgraph[(size_t)(rowBase + r) * MAX_NB + j];
        ptr_s[r][j] = (id < M_N) ? (g_tmsgh + (size_t)id * HD)
                                 : (gsrc + (size_t)(id - M_N) * HD);
    }
    __syncthreads();

    const int r   = tid >> 2;              // [0,64) gather row
    const int kq8 = (tid & 3) << 3;        // {0,8,16,24}
    const int tx = tid & 15;
    const int ty = tid >> 4;
    float acc[4][16] = {};

    #pragma unroll 1
    for (int k0 = 0; k0 < HD; k0 += 64) {
        // gather 64-wide K slice: 2 x 16 B per lane; 4 lanes cover one 128 B line
        float s[16];
        #pragma unroll
        for (int t = 0; t < 16; ++t) s[t] = 0.f;
        #pragma unroll
        for (int j = 0; j < MAX_NB; ++j) {
            const u16* p = ptr_s[r][j] + k0 + kq8;
            const uint4 v0 = *(const uint4*)(p);
            const uint4 v1 = *(const uint4*)(p + 32);
            s[0]  += blo(v0.x); s[1]  += bhi(v0.x);
            s[2]  += blo(v0.y); s[3]  += bhi(v0.y);
            s[4]  += blo(v0.z); s[5]  += bhi(v0.z);
            s[6]  += blo(v0.w); s[7]  += bhi(v0.w);
            s[8]  += blo(v1.x); s[9]  += bhi(v1.x);
            s[10] += blo(v1.y); s[11] += bhi(v1.y);
            s[12] += blo(v1.z); s[13] += bhi(v1.z);
            s[14] += blo(v1.w); s[15] += bhi(v1.w);
        }
        #pragma unroll
        for (int t = 0; t < 8; ++t) As[kq8 + t][r] = s[t];
        #pragma unroll
        for (int t = 0; t < 8; ++t) As[32 + kq8 + t][r] = s[8 + t];

        // two 32-row Wh half-slices (Bs reused)
        #pragma unroll 1
        for (int h2 = 0; h2 < 2; ++h2) {
            #pragma unroll
            for (int i = 0; i < 8; ++i) {
                const int idx = tid + i * 256;
                const int kk = idx >> 6;
                const int c4 = (idx & 63) << 2;
                *(float4*)&Bs[kk][c4] =
                    *(const float4*)(Wh + (size_t)(k0 + 32 * h2 + kk) * HD + c4);
            }
            __syncthreads();
            #pragma unroll 4
            for (int kk = 0; kk < 32; ++kk) {
                const float4 a = *(const float4*)&As[32 * h2 + kk][ty * 4];
                const float av[4] = {a.x, a.y, a.z, a.w};
                #pragma unroll
                for (int g = 0; g < 4; ++g) {
                    const float4 b = *(const float4*)&Bs[kk][g * 64 + tx * 4];
                    const float bv[4] = {b.x, b.y, b.z, b.w};
                    #pragma unroll
                    for (int i = 0; i < 4; ++i)
                        #pragma unroll
                        for (int q = 0; q < 4; ++q)
                            acc[i][g * 4 + q] += av[i] * bv[q];
                }
            }
            __syncthreads();
        }
    }

    // ---- epilogue, fully static: acc stays in VGPRs ----
    // stage fbonds block rows into LDS (As overlay) + W_i cols [0,128) (Bs overlay)
    for (int idx = tid; idx < BM * 10; idx += 256) {
        const int rr = idx / 10;
        const int q = idx - rr * 10;
        *(float4*)&fb_s[rr][q * 4] =
            *(const float4*)(fbonds + (size_t)(rowBase + rr) * FB_DIM + q * 4);
    }
    #pragma unroll
    for (int i = 0; i < 5; ++i) {
        const int idx = tid + i * 256;
        const int k = idx >> 5;
        const int c4 = (idx & 31) << 2;
        *(float4*)&wi_s[k][c4] = *(const float4*)(Wi + (size_t)k * HD + c4);
    }
    __syncthreads();

    // h = 0 : cols [0,128)
    #pragma unroll
    for (int i = 0; i < 4; ++i) {
        const int lr = ty * 4 + i;
        float a0 = acc[i][0], a1 = acc[i][1], a2 = acc[i][2], a3 = acc[i][3];
        float a4 = acc[i][4], a5 = acc[i][5], a6 = acc[i][6], a7 = acc[i][7];
        #pragma unroll
        for (int k = 0; k < FB_DIM; ++k) {
            const float f = fb_s[lr][k];
            const float4 b0 = *(const float4*)&wi_s[k][tx * 4];
            const float4 b1 = *(const float4*)&wi_s[k][64 + tx * 4];
            a0 += f * b0.x; a1 += f * b0.y; a2 += f * b0.z; a3 += f * b0.w;
            a4 += f * b1.x; a5 += f * b1.y; a6 += f * b1.z; a7 += f * b1.w;
        }
        const size_t base = (size_t)(rowBase + lr) * HD;
        ushort4 o0, o1;
        o0.x = f2b(fmaxf(a0, 0.f)); o0.y = f2b(fmaxf(a1, 0.f));
        o0.z = f2b(fmaxf(a2, 0.f)); o0.w = f2b(fmaxf(a3, 0.f));
        o1.x = f2b(fmaxf(a4, 0.f)); o1.y = f2b(fmaxf(a5, 0.f));
        o1.z = f2b(fmaxf(a6, 0.f)); o1.w = f2b(fmaxf(a7, 0.f));
        *(ushort4*)(gdst + base + tx * 4) = o0;
        *(ushort4*)(gdst + base + 64 + tx * 4) = o1;
    }
    __syncthreads();
    // reload W_i cols [128,256)
    #pragma unroll
    for (int i = 0; i < 5; ++i) {
        const int idx = tid + i * 256;
        const int k = idx >> 5;
        const int c4 = (idx & 31) << 2;
        *(float4*)&wi_s[k][c4] = *(const float4*)(Wi + (size_t)k * HD + 128 + c4);
    }
    __syncthreads();
    // h = 1 : cols [128,256)
    #pragma unroll
    for (int i = 0; i < 4; ++i) {
        const int lr = ty * 4 + i;
        float a0 = acc[i][8],  a1 = acc[i][9],  a2 = acc[i][10], a3 = acc[i][11];
        float a4 = acc[i][12], a5 = acc[i][13], a6 = acc[i][14], a7 = acc[i][15];
        #pragma unroll
        for (int k = 0; k < FB_DIM; ++k) {
            const float f = fb_s[lr][k];
            const float4 b0 = *(const float4*)&wi_s[k][tx * 4];
            const float4 b1 = *(const float4*)&wi_s[k][64 + tx * 4];
            a0 += f * b0.x; a1 += f * b0.y; a2 += f * b0.z; a3 += f * b0.w;
            a4 += f * b1.x; a5 += f * b1.y; a6 += f * b1.z; a7 += f * b1.w;
        }
        const size_t base = (size_t)(rowBase + lr) * HD + 128;
        ushort4 o0, o1;
        o0.x = f2b(fmaxf(a0, 0.f)); o0.y = f2b(fmaxf(a1, 0.f));
        o0.z = f2b(fmaxf(a2, 0.f)); o0.w = f2b(fmaxf(a3, 0.f));
        o1.x = f2b(fmaxf(a4, 0.f)); o1.y = f2b(fmaxf(a5, 0.f));
        o1.z = f2b(fmaxf(a6, 0.f)); o1.w = f2b(fmaxf(a7, 0.f));
        *(ushort4*)(gdst + base + tx * 4) = o0;
        *(ushort4*)(gdst + base + 64 + tx * 4) = o1;
    }
}

// ------- K3: out += segsum(relu([fatoms|gather(agraph,msg)] @ W_o + b)) -------
// virtual A layout (K=320): [0,35)=fatoms, [35,40)=0, [40,296)=gather(bf16), [296,320)=0
// B rows remapped: kg<35 -> Wo[kg]; 40<=kg<296 -> Wo[kg-5]; else 0.
__global__ __launch_bounds__(256, 3)
void k_final(const int* __restrict__ agraph, const float* __restrict__ fatoms,
             const float* __restrict__ Wo, const float* __restrict__ bias,
             const int* __restrict__ scope, float* __restrict__ outsum)
{
    const u16* gm = g_msg0;
    __shared__ float As[32][68];
    __shared__ float Bs[32][260];
    __shared__ const u16* ptr_s[BM][MAX_NB];
    const int tid = threadIdx.x;
    const int rowBase = blockIdx.x * BM;

    for (int idx = tid; idx < BM * MAX_NB; idx += 256) {
        const int rr = idx / MAX_NB;
        const int j = idx - rr * MAX_NB;
        const int ra = rowBase + rr;
        const int id = (ra < A_N) ? agraph[(size_t)ra * MAX_NB + j] : 0;  // tmsg row0 = 0
        ptr_s[rr][j] = (id < M_N) ? (g_tmsgh + (size_t)id * HD)
                                  : (gm + (size_t)(id - M_N) * HD);
    }
    __syncthreads();

    const int r   = tid >> 2;
    const int kq8 = (tid & 3) << 3;
    const int ra  = rowBase + r;
    const bool va = ra < A_N;
    const int tx = tid & 15;
    const int ty = tid >> 4;
    float acc[4][16] = {};

    #pragma unroll 1
    for (int k0 = 0; k0 < 320; k0 += 32) {
        const int k = k0 + kq8;
        if (k >= 40 && k < 296) {
            const int off = k - 40;
            float s[8] = {0.f,0.f,0.f,0.f,0.f,0.f,0.f,0.f};
            #pragma unroll
            for (int j = 0; j < MAX_NB; ++j) {
                const uint4 v = *(const uint4*)(ptr_s[r][j] + off);
                s[0] += blo(v.x); s[1] += bhi(v.x);
                s[2] += blo(v.y); s[3] += bhi(v.y);
                s[4] += blo(v.z); s[5] += bhi(v.z);
                s[6] += blo(v.w); s[7] += bhi(v.w);
            }
            #pragma unroll
            for (int t = 0; t < 8; ++t) As[kq8 + t][r] = s[t];
        } else {
            #pragma unroll
            for (int t = 0; t < 8; ++t) {
                const int kk2 = k + t;
                float x = 0.f;
                if (kk2 < ATOM_FDIM && va) x = fatoms[(size_t)ra * ATOM_FDIM + kk2];
                As[kq8 + t][r] = x;
            }
        }
        #pragma unroll
        for (int i = 0; i < 8; ++i) {
            const int idx = tid + i * 256;
            const int kk = idx >> 6;
            const int c4 = (idx & 63) << 2;
            const int kg = k0 + kk;
            float4 v = {0.f, 0.f, 0.f, 0.f};
            if (kg < ATOM_FDIM)
                v = *(const float4*)(Wo + (size_t)kg * HD + c4);
            else if (kg >= 40 && kg < 296)
                v = *(const float4*)(Wo + (size_t)(kg - 5) * HD + c4);
            *(float4*)&Bs[kk][c4] = v;
        }
        __syncthreads();
        #pragma unroll 4
        for (int kk = 0; kk < 32; ++kk) {
            const float4 a = *(const float4*)&As[kk][ty * 4];
            const float av[4] = {a.x, a.y, a.z, a.w};
            #pragma unroll
            for (int g = 0; g < 4; ++g) {
                const float4 b = *(const float4*)&Bs[kk][g * 64 + tx * 4];
                const float bv[4] = {b.x, b.y, b.z, b.w};
                #pragma unroll
                for (int i = 0; i < 4; ++i)
                    #pragma unroll
                    for (int q = 0; q < 4; ++q)
                        acc[i][g * 4 + q] += av[i] * bv[q];
            }
        }
        __syncthreads();
    }

    float bb[16];
    #pragma unroll
    for (int g = 0; g < 4; ++g) {
        const float4 b = *(const float4*)(bias + g * 64 + tx * 4);
        bb[g*4+0] = b.x; bb[g*4+1] = b.y; bb[g*4+2] = b.z; bb[g*4+3] = b.w;
    }
    float s[16] = {};
    int prev = -1;
    #pragma unroll    // static i -> acc stays in registers (this was `unroll 1` in R6!)
    for (int i = 0; i < 4; ++i) {
        const int rr = rowBase + ty * 4 + i;
        if (rr < A_N) {
            const int m = scope[rr];
            if (m != prev) {
                if (prev >= 0) {
                    float* dst = outsum + (size_t)prev * HD;
                    #pragma unroll
                    for (int g = 0; g < 4; ++g)
                        #pragma unroll
                        for (int q = 0; q < 4; ++q)
                            atomicAdd(dst + g * 64 + tx * 4 + q, s[g * 4 + q]);
                    #pragma unroll
                    for (int q = 0; q < 16; ++q) s[q] = 0.f;
                }
                prev = m;
            }
            #pragma unroll
            for (int q = 0; q < 16; ++q)
                s[q] += fmaxf(acc[i][q] + bb[q], 0.f);
        }
    }
    if (prev >= 0) {
        float* dst = outsum + (size_t)prev * HD;
        #pragma unroll
        for (int g = 0; g < 4; ++g)
            #pragma unroll
            for (int q = 0; q < 4; ++q)
                atomicAdd(dst + g * 64 + tx * 4 + q, s[g * 4 + q]);
    }
}

// ---------------- counts + divide ----------------
__global__ __launch_bounds__(256)
void k_counts(const int* __restrict__ scope)
{
    const int a = blockIdx.x * 256 + threadIdx.x;
    if (a < A_N) atomicAdd(&g_counts[scope[a]], 1.0f);
}

__global__ __launch_bounds__(256)
void k_div(float* __restrict__ out)
{
    const int idx = blockIdx.x * 256 + threadIdx.x;
    out[idx] = out[idx] / fmaxf(g_counts[idx >> 8], 1.0f);
}

// ---------------- launch ----------------
extern "C" void kernel_launch(void* const* d_in, const int* in_sizes, int n_in,
                              void* d_out, int out_size, void* d_ws, size_t ws_size,
                              hipStream_t stream)
{
    const float* fatoms = (const float*)d_in[0];
    const float* fbonds = (const float*)d_in[1];
    const int*   agraph = (const int*)d_in[2];
    const int*   bgraph = (const int*)d_in[3];
    const float* tmsg   = (const float*)d_in[4];
    const int*   scope  = (const int*)d_in[5];
    const float* W_i    = (const float*)d_in[6];
    const float* W_h    = (const float*)d_in[7];
    const float* W_o    = (const float*)d_in[8];
    const float* W_ob   = (const float*)d_in[9];
    float* out = (float*)d_out;

    (void)d_ws; (void)ws_size;

    k_zero_out<<<(N_MOLS * HD + 255) / 256, 256, 0, stream>>>(out, N_MOLS * HD);
    k_zero_counts<<<(N_MOLS + 255) / 256, 256, 0, stream>>>();
    k_cvt<<<(M_N * HD / 4 + 255) / 256, 256, 0, stream>>>(tmsg);

    k_in<<<4096, 256, 0, stream>>>(fbonds, W_i);
    k_mp<<<B_N / BM, 256, 0, stream>>>(bgraph, W_h, fbonds, W_i, 0);
    k_mp<<<B_N / BM, 256, 0, stream>>>(bgraph, W_h, fbonds, W_i, 1);
    k_counts<<<(A_N + 255) / 256, 256, 0, stream>>>(scope);
    k_final<<<(A_N + BM - 1) / BM, 256, 0, stream>>>(agraph, fatoms, W_o, W_ob, scope, out);
    k_div<<<(N_MOLS * HD) / 256, 256, 0, stream>>>(out);
}